// Round 6
// baseline (400.050 us; speedup 1.0000x reference)
//
#include <hip/hip_runtime.h>
#include <stdint.h>

#define B_SZ 4096
#define K_SZ 4
#define D_SZ 1024
#define INV_T 14.285714285714286f   // 1/0.07

typedef __attribute__((ext_vector_type(8))) short bf16x8_t;  // 8 bf16 in 4 VGPRs
typedef __attribute__((ext_vector_type(4))) float f32x4_t;   // MFMA accumulator
typedef unsigned short u16;

#define CFENCE() asm volatile("" ::: "memory")

// fp32 -> bf16 by truncation
static __device__ __forceinline__ u16 f2bf(float f) {
    union { float f; uint32_t u; } v; v.f = f;
    return (u16)(v.u >> 16);
}

// async global->LDS, 16 bytes per lane. Dest must be wave-uniform base +
// lane*16 (linear in thread id within the wave).
static __device__ __forceinline__ void gl_lds16(const u16* g, u16* l) {
    __builtin_amdgcn_global_load_lds(
        (const __attribute__((address_space(1))) void*)g,
        (__attribute__((address_space(3))) void*)l, 16, 0, 0);
}

// ===========================================================================
// MAIN PATH (needs ~48.2 MB of d_ws)
// ===========================================================================

// ---------------------------------------------------------------------------
// Pass 1: wave-per-row convert + diagonal dots. Blocks 0..2 additionally
// zero rs1/cs1/rs2 (12288 floats). No LDS, no __syncthreads.
// ---------------------------------------------------------------------------
__global__ __launch_bounds__(256) void convert_diag4z(
    const float* __restrict__ img, const float* __restrict__ txt,
    const float* __restrict__ other,
    u16* __restrict__ img_bf, u16* __restrict__ txt_bf, u16* __restrict__ oth_bf,
    float* __restrict__ partials, float* __restrict__ zero_region)
{
    if (blockIdx.x < 3) {
        float4* z = (float4*)zero_region + (size_t)blockIdx.x * 1024;
#pragma unroll
        for (int k = 0; k < 4; ++k)
            z[k * 256 + threadIdx.x] = (float4){0.f, 0.f, 0.f, 0.f};
    }

    const int wave = threadIdx.x >> 6;
    const int lane = threadIdx.x & 63;
    const int row  = blockIdx.x * 4 + wave;

    const float* src;
    const float* dotsrc = nullptr;
    u16* dst;
    float* part = nullptr;

    if (row < B_SZ) {
        src    = img + (size_t)row * D_SZ;
        dst    = img_bf + (size_t)row * D_SZ;
        dotsrc = txt + (size_t)row * D_SZ;
        part   = partials + row;                       // -> dsum pool
    } else if (row < 2 * B_SZ) {
        const int r = row - B_SZ;
        src = txt + (size_t)r * D_SZ;
        dst = txt_bf + (size_t)r * D_SZ;
    } else {
        const int r = row - 2 * B_SZ;                  // 0..16383
        src    = other + (size_t)r * D_SZ;
        dst    = oth_bf + (size_t)r * D_SZ;
        dotsrc = txt + (size_t)(r >> 2) * D_SZ;
        part   = partials + B_SZ + r;                  // -> msum pool
    }

    float s = 0.f;
#pragma unroll
    for (int it = 0; it < 4; ++it) {
        const int off = (it * 64 + lane) * 4;
        float4 a = *(const float4*)(src + off);
        ushort4 ua;
        ua.x = f2bf(a.x); ua.y = f2bf(a.y); ua.z = f2bf(a.z); ua.w = f2bf(a.w);
        *(ushort4*)(dst + off) = ua;
        if (dotsrc) {
            float4 b = *(const float4*)(dotsrc + off);
            s += a.x * b.x + a.y * b.y + a.z * b.z + a.w * b.w;
        }
    }
    if (part) {
#pragma unroll
        for (int d = 1; d < 64; d <<= 1) s += __shfl_xor(s, d);
        if (lane == 0) part[0] = s * INV_T;
    }
}

// ---------------------------------------------------------------------------
// Pass 2 (R6): 128x256-tile, BK=32, 8-wave (2Mx4N, per-wave 64x64 -> acc[4][4]
// = 64 regs), double-buffered, LDS 48 KiB, __launch_bounds__(512,4) ->
// TWO blocks per CU. Rationale: R2's 256x256 config (128 KiB LDS, ~244
// unified regs/wave) pinned occupancy at 1 block/CU, so the per-tile
// vmcnt(0)+barrier drain was a full-CU stall (12x gap to MFMA floor).
// Co-resident blocks run anti-phase and hide each other's drains (m97/m114
// precedent: same 2-barrier structure at ~3 blocks/CU hit 874 TF).
//
// LDS swizzle for 32-u16 rows: chunk ^= (row>>1)&3 (2-way bank alias = free),
// applied BOTH sides: inverse on the gl_lds16 global source, forward on the
// ds_read address.
//
// One dispatch: blocks 0..511 = img x txt (row+col sums),
// 512..2559 = txt x oth (rowsum only).
// ---------------------------------------------------------------------------
__global__ __launch_bounds__(512, 4) void gemm_fused(
    const u16* __restrict__ img_bf, const u16* __restrict__ txt_bf,
    const u16* __restrict__ oth_bf, float* __restrict__ rs1,
    float* __restrict__ cs1, float* __restrict__ rs2)
{
    __shared__ u16 lds_a[2][128][32];   // 2 x 8 KiB
    __shared__ u16 lds_b[2][256][32];   // 2 x 16 KiB   (total 48 KiB)

    // segment select + XCD-aware chunked swizzle (both segments /8)
    const int bid0 = blockIdx.x;
    const u16 *X, *Y;
    float *rowsum, *colsum;
    int lb, gx, nloc;
    if (bid0 < 512) {
        X = img_bf; Y = txt_bf; rowsum = rs1; colsum = cs1;
        lb = bid0;       gx = 16; nloc = 512;
    } else {
        X = txt_bf; Y = oth_bf; rowsum = rs2; colsum = nullptr;
        lb = bid0 - 512; gx = 64; nloc = 2048;
    }
    const int chunk = nloc >> 3;
    lb = (lb & 7) * chunk + (lb >> 3);
    const int m0 = (lb / gx) * 128;
    const int n0 = (lb % gx) * 256;

    const int t    = threadIdx.x;
    const int lane = t & 63;
    const int w    = t >> 6;          // 0..7
    const int wrm  = (w >> 2) * 64;   // wave M offset (0/64)
    const int wcn  = (w & 3) * 64;    // wave N offset (0/64/128/192)
    const int lr   = lane & 15;
    const int q    = lane >> 4;
    const int ch   = q ^ ((lr >> 1) & 3);   // swizzled 16B-chunk index

    // staging offsets. A tile: 128x32 u16 = 512 chunks of 16B (1/thread).
    // B tile: 256x32 = 1024 chunks (2/thread). Chunk c -> row c>>2, logical
    // slot (c&3); global slot inverse-swizzled: (c&3) ^ ((row>>1)&3).
    const int rA    = t >> 2;
    const int goffA = rA * D_SZ + ((t & 3) ^ ((rA >> 1) & 3)) * 8;
    const int loffA = t * 8;
    int goffB[2], loffB[2];
#pragma unroll
    for (int i = 0; i < 2; ++i) {
        const int c  = i * 512 + t;
        const int r  = c >> 2;
        goffB[i] = r * D_SZ + ((c & 3) ^ ((r >> 1) & 3)) * 8;
        loffB[i] = c * 8;
    }

    const u16* gA = X + (size_t)m0 * D_SZ;
    const u16* gB = Y + (size_t)n0 * D_SZ;

    auto stage = [&](int buf, int k0) {
        gl_lds16(gA + k0 + goffA, &lds_a[buf][0][0] + loffA);
#pragma unroll
        for (int i = 0; i < 2; ++i)
            gl_lds16(gB + k0 + goffB[i], &lds_b[buf][0][0] + loffB[i]);
    };

    f32x4_t acc[4][4];
#pragma unroll
    for (int i = 0; i < 4; ++i)
#pragma unroll
        for (int jj = 0; jj < 4; ++jj) acc[i][jj] = (f32x4_t){0.f, 0.f, 0.f, 0.f};

    // ---- prologue: stage tile 0 into buf 0, wait, barrier ----
    stage(0, 0);
    asm volatile("s_waitcnt vmcnt(0)" ::: "memory");
    __builtin_amdgcn_s_barrier();
    CFENCE();

    const int NT = D_SZ / 32;   // 32
    for (int j = 0; j < NT; ++j) {
        const int c = j & 1;

        // prefetch tile j+1 into the other buffer (flies under compute)
        if (j + 1 < NT) stage(c ^ 1, (j + 1) * 32);

        bf16x8_t bfr[4], afr[4];
#pragma unroll
        for (int nt = 0; nt < 4; ++nt)
            bfr[nt] = *(const bf16x8_t*)(&lds_b[c][0][0] + (wcn + nt * 16 + lr) * 32 + ch * 8);
#pragma unroll
        for (int mt = 0; mt < 4; ++mt)
            afr[mt] = *(const bf16x8_t*)(&lds_a[c][0][0] + (wrm + mt * 16 + lr) * 32 + ch * 8);

#pragma unroll
        for (int mt = 0; mt < 4; ++mt)
#pragma unroll
            for (int nt = 0; nt < 4; ++nt)
                acc[mt][nt] = __builtin_amdgcn_mfma_f32_16x16x32_bf16(
                    afr[mt], bfr[nt], acc[mt][nt], 0, 0, 0);

        // tile boundary: next tile's loads landed (issued a tile ago); all
        // waves done reading buf c.
        asm volatile("s_waitcnt vmcnt(0)" ::: "memory");
        __builtin_amdgcn_s_barrier();
        CFENCE();
    }

    // Epilogue. C/D layout: row = wrm + mt*16 + q*4 + r, col = wcn + nt*16 + lr.
    float rowp[4][4];
#pragma unroll
    for (int mt = 0; mt < 4; ++mt)
#pragma unroll
        for (int r = 0; r < 4; ++r) rowp[mt][r] = 0.f;

#pragma unroll
    for (int nt = 0; nt < 4; ++nt) {
        float colp = 0.f;
#pragma unroll
        for (int mt = 0; mt < 4; ++mt) {
#pragma unroll
            for (int r = 0; r < 4; ++r) {
                float e = __expf(acc[mt][nt][r] * INV_T);
                colp += e;
                rowp[mt][r] += e;
            }
        }
        if (colsum) {
            colp += __shfl_xor(colp, 16);
            colp += __shfl_xor(colp, 32);
            if (q == 0)
                atomicAdd(&colsum[n0 + wcn + nt * 16 + lr], colp);
        }
    }
#pragma unroll
    for (int mt = 0; mt < 4; ++mt) {
#pragma unroll
        for (int r = 0; r < 4; ++r) {
            float rp = rowp[mt][r];
            rp += __shfl_xor(rp, 1);
            rp += __shfl_xor(rp, 2);
            rp += __shfl_xor(rp, 4);
            rp += __shfl_xor(rp, 8);
            if (lr == 0)
                atomicAdd(&rowsum[m0 + wrm + mt * 16 + 4 * q + r], rp);
        }
    }
}

// ---------------------------------------------------------------------------
// Finalize: one 1024-thread block, float4 loads, wave shuffle + LDS reduce.
// ---------------------------------------------------------------------------
__global__ __launch_bounds__(1024) void finalize_wide(
    const float* __restrict__ rs1, const float* __restrict__ cs1,
    const float* __restrict__ rs2, const float* __restrict__ partials,
    float* __restrict__ out)
{
    const int t = threadIdx.x;   // 0..1023

    float4 a = ((const float4*)rs1)[t];
    float4 b = ((const float4*)cs1)[t];
    float4 c = ((const float4*)rs2)[t];
    float4 p = ((const float4*)partials)[t];
    float4 m0 = ((const float4*)(partials + B_SZ))[t];
    float4 m1 = ((const float4*)(partials + B_SZ))[t + 1024];
    float4 m2 = ((const float4*)(partials + B_SZ))[t + 2048];
    float4 m3 = ((const float4*)(partials + B_SZ))[t + 3072];
    float4 m4 = ((const float4*)(partials + B_SZ))[t + 4096];

    float s1 = __logf(a.x) + __logf(a.y) + __logf(a.z) + __logf(a.w);
    float s2 = __logf(b.x) + __logf(b.y) + __logf(b.z) + __logf(b.w);
    float s3 = __logf(c.x) + __logf(c.y) + __logf(c.z) + __logf(c.w);
    float pd = p.x + p.y + p.z + p.w;
    float pm = (m0.x + m0.y + m0.z + m0.w) + (m1.x + m1.y + m1.z + m1.w)
             + (m2.x + m2.y + m2.z + m2.w) + (m3.x + m3.y + m3.z + m3.w)
             + (m4.x + m4.y + m4.z + m4.w);

#pragma unroll
    for (int d = 1; d < 64; d <<= 1) {
        s1 += __shfl_xor(s1, d); s2 += __shfl_xor(s2, d);
        s3 += __shfl_xor(s3, d); pd += __shfl_xor(pd, d);
        pm += __shfl_xor(pm, d);
    }
    __shared__ float red[5][16];
    const int w = t >> 6, lane = t & 63;
    if (lane == 0) {
        red[0][w] = s1; red[1][w] = s2; red[2][w] = s3;
        red[3][w] = pd; red[4][w] = pm;
    }
    __syncthreads();
    if (t == 0) {
        float S1 = 0.f, S2 = 0.f, S3 = 0.f, DS = 0.f, MS = 0.f;
#pragma unroll
        for (int i = 0; i < 16; ++i) {
            S1 += red[0][i]; S2 += red[1][i]; S3 += red[2][i];
            DS += red[3][i]; MS += red[4][i];
        }
        const float invB = 1.0f / (float)B_SZ;
        out[0] = 0.5f * (S1 + S2) * invB - DS * invB
               + 0.5f * (S3 * invB - MS / ((float)B_SZ * K_SZ));
    }
}

// ===========================================================================
// FALLBACK PATH (used only if d_ws is too small) ----------------------------
// ===========================================================================
template <bool COLSUM>
__global__ __launch_bounds__(256) void gemm_expsum(
    const float* __restrict__ X, const float* __restrict__ Y,
    float* __restrict__ rowsum, float* __restrict__ colsum)
{
    __shared__ u16 As[128][32];
    __shared__ u16 Bs[128][32];
    const int m0 = blockIdx.y * 128, n0 = blockIdx.x * 128;
    const int tid = threadIdx.x, lane = tid & 63, w = tid >> 6;
    const int wm = (w & 1) * 64, wn = (w >> 1) * 64;
    const int lr = lane & 15, q = lane >> 4;
    f32x4_t acc[4][4];
#pragma unroll
    for (int i = 0; i < 4; i++)
#pragma unroll
        for (int j = 0; j < 4; j++) acc[i][j] = (f32x4_t){0.f, 0.f, 0.f, 0.f};
    const int kv = (tid & 7) * 4, r0 = tid >> 3;
    const float* xb = X + (size_t)(m0 + r0) * D_SZ + kv;
    const float* yb = Y + (size_t)(n0 + r0) * D_SZ + kv;
    for (int k0 = 0; k0 < D_SZ; k0 += 32) {
#pragma unroll
        for (int i = 0; i < 4; i++) {
            float4 a = *(const float4*)(xb + (size_t)(32 * i) * D_SZ + k0);
            float4 b = *(const float4*)(yb + (size_t)(32 * i) * D_SZ + k0);
            ushort4 ua, ub;
            ua.x = f2bf(a.x); ua.y = f2bf(a.y); ua.z = f2bf(a.z); ua.w = f2bf(a.w);
            ub.x = f2bf(b.x); ub.y = f2bf(b.y); ub.z = f2bf(b.z); ub.w = f2bf(b.w);
            *(ushort4*)&As[r0 + 32 * i][kv] = ua;
            *(ushort4*)&Bs[r0 + 32 * i][kv] = ub;
        }
        __syncthreads();
        bf16x8_t af[4], bfr[4];
#pragma unroll
        for (int mt = 0; mt < 4; mt++)
            af[mt] = *(const bf16x8_t*)&As[wm + 16 * mt + lr][8 * q];
#pragma unroll
        for (int nt = 0; nt < 4; nt++)
            bfr[nt] = *(const bf16x8_t*)&Bs[wn + 16 * nt + lr][8 * q];
#pragma unroll
        for (int mt = 0; mt < 4; mt++)
#pragma unroll
            for (int nt = 0; nt < 4; nt++)
                acc[mt][nt] = __builtin_amdgcn_mfma_f32_16x16x32_bf16(
                    af[mt], bfr[nt], acc[mt][nt], 0, 0, 0);
        __syncthreads();
    }
    float rowp[4][4];
#pragma unroll
    for (int mt = 0; mt < 4; mt++)
#pragma unroll
        for (int r = 0; r < 4; r++) rowp[mt][r] = 0.f;
#pragma unroll
    for (int nt = 0; nt < 4; nt++) {
        float colp = 0.f;
#pragma unroll
        for (int mt = 0; mt < 4; mt++)
#pragma unroll
            for (int r = 0; r < 4; r++) {
                float e = __expf(acc[mt][nt][r] * INV_T);
                colp += e; rowp[mt][r] += e;
            }
        if (COLSUM) {
            colp += __shfl_xor(colp, 16);
            colp += __shfl_xor(colp, 32);
            if (q == 0) atomicAdd(&colsum[n0 + wn + 16 * nt + lr], colp);
        }
    }
#pragma unroll
    for (int mt = 0; mt < 4; mt++)
#pragma unroll
        for (int r = 0; r < 4; r++) {
            float rp = rowp[mt][r];
            rp += __shfl_xor(rp, 1); rp += __shfl_xor(rp, 2);
            rp += __shfl_xor(rp, 4); rp += __shfl_xor(rp, 8);
            if (lr == 0) atomicAdd(&rowsum[m0 + wm + 16 * mt + 4 * q + r], rp);
        }
}

__global__ __launch_bounds__(256) void diag_kernel(
    const float* __restrict__ img, const float* __restrict__ txt,
    const float* __restrict__ other, float* __restrict__ dm)
{
    const int gw = blockIdx.x * 4 + (threadIdx.x >> 6);
    const int lane = threadIdx.x & 63;
    const float *pa, *pb; float* target;
    if (gw < B_SZ) {
        pa = img + (size_t)gw * D_SZ; pb = txt + (size_t)gw * D_SZ; target = dm;
    } else {
        const int g2 = gw - B_SZ;
        pa = other + (size_t)g2 * D_SZ; pb = txt + (size_t)(g2 >> 2) * D_SZ;
        target = dm + 1;
    }
    float s = 0.f;
#pragma unroll
    for (int j = 0; j < 4; j++) {
        float4 a = *(const float4*)(pa + 4 * (lane + 64 * j));
        float4 b = *(const float4*)(pb + 4 * (lane + 64 * j));
        s += a.x * b.x + a.y * b.y + a.z * b.z + a.w * b.w;
    }
#pragma unroll
    for (int d = 1; d < 64; d <<= 1) s += __shfl_xor(s, d);
    if (lane == 0) atomicAdd(target, s * INV_T);
}

__global__ __launch_bounds__(256) void finalize_atomic(
    const float* __restrict__ rs1, const float* __restrict__ cs1,
    const float* __restrict__ rs2, const float* __restrict__ dm,
    float* __restrict__ out)
{
    float s1 = 0.f, s2 = 0.f, s3 = 0.f;
    for (int i = threadIdx.x; i < B_SZ; i += 256) {
        s1 += __logf(rs1[i]); s2 += __logf(cs1[i]); s3 += __logf(rs2[i]);
    }
#pragma unroll
    for (int d = 1; d < 64; d <<= 1) {
        s1 += __shfl_xor(s1, d); s2 += __shfl_xor(s2, d); s3 += __shfl_xor(s3, d);
    }
    __shared__ float red[3][4];
    const int w = threadIdx.x >> 6, lane = threadIdx.x & 63;
    if (lane == 0) { red[0][w] = s1; red[1][w] = s2; red[2][w] = s3; }
    __syncthreads();
    if (threadIdx.x == 0) {
        float S1 = red[0][0] + red[0][1] + red[0][2] + red[0][3];
        float S2 = red[1][0] + red[1][1] + red[1][2] + red[1][3];
        float S3 = red[2][0] + red[2][1] + red[2][2] + red[2][3];
        const float invB = 1.0f / (float)B_SZ;
        out[0] = 0.5f * (S1 + S2) * invB - dm[0] * invB
               + 0.5f * (S3 * invB - dm[1] / ((float)B_SZ * K_SZ));
    }
}

// ===========================================================================
extern "C" void kernel_launch(void* const* d_in, const int* in_sizes, int n_in,
                              void* d_out, int out_size, void* d_ws, size_t ws_size,
                              hipStream_t stream) {
    const float* img   = (const float*)d_in[0];
    const float* txt   = (const float*)d_in[1];
    const float* other = (const float*)d_in[2];
    float* out = (float*)d_out;
    float* ws  = (float*)d_ws;

    // float-region layout
    float* rs1      = ws;                    // [4096]
    float* cs1      = ws + B_SZ;             // [4096]
    float* rs2      = ws + 2 * B_SZ;         // [4096]
    float* partials = ws + 3 * B_SZ;         // [20480]  (main path)
    float* dm       = ws + 3 * B_SZ;         // [2]      (fallback path)

    const size_t hdr_floats = 3 * B_SZ + B_SZ + B_SZ * K_SZ;   // 32768
    const size_t bf_bytes   = (size_t)(2 * B_SZ + B_SZ * K_SZ) * D_SZ * 2; // 48 MB
    const size_t need = hdr_floats * sizeof(float) + bf_bytes;

    if (ws_size >= need) {
        u16* img_bf = (u16*)(ws + hdr_floats);
        u16* txt_bf = img_bf + (size_t)B_SZ * D_SZ;
        u16* oth_bf = txt_bf + (size_t)B_SZ * D_SZ;

        hipLaunchKernelGGL(convert_diag4z, dim3((2 * B_SZ + B_SZ * K_SZ) / 4),
                           dim3(256), 0, stream, img, txt, other,
                           img_bf, txt_bf, oth_bf, partials, rs1);
        hipLaunchKernelGGL(gemm_fused, dim3(2560), dim3(512), 0, stream,
                           img_bf, txt_bf, oth_bf, rs1, cs1, rs2);
        hipLaunchKernelGGL(finalize_wide, dim3(1), dim3(1024), 0, stream,
                           rs1, cs1, rs2, partials, out);
    } else {
        hipMemsetAsync(d_ws, 0, (3 * B_SZ + 2) * sizeof(float), stream);
        hipLaunchKernelGGL((gemm_expsum<true>), dim3(B_SZ / 128, B_SZ / 128),
                           dim3(256), 0, stream, img, txt, rs1, cs1);
        hipLaunchKernelGGL((gemm_expsum<false>),
                           dim3(B_SZ * K_SZ / 128, B_SZ / 128), dim3(256), 0,
                           stream, txt, other, rs2, nullptr);
        hipLaunchKernelGGL(diag_kernel, dim3((B_SZ + B_SZ * K_SZ) / 4),
                           dim3(256), 0, stream, img, txt, other, dm);
        hipLaunchKernelGGL(finalize_atomic, dim3(1), dim3(256), 0, stream,
                           rs1, cs1, rs2, dm, out);
    }
}

// Round 7
// 342.204 us; speedup vs baseline: 1.1690x; 1.1690x over previous
//
#include <hip/hip_runtime.h>
#include <stdint.h>

#define B_SZ 4096
#define K_SZ 4
#define D_SZ 1024
#define INV_T 14.285714285714286f   // 1/0.07

typedef __attribute__((ext_vector_type(8))) short bf16x8_t;  // 8 bf16 in 4 VGPRs
typedef __attribute__((ext_vector_type(4))) float f32x4_t;   // MFMA accumulator
typedef unsigned short u16;

#define CFENCE() asm volatile("" ::: "memory")

// fp32 -> bf16 by truncation
static __device__ __forceinline__ u16 f2bf(float f) {
    union { float f; uint32_t u; } v; v.f = f;
    return (u16)(v.u >> 16);
}

static __device__ __forceinline__ bf16x8_t pack8(float4 x, float4 y) {
    bf16x8_t r;
    r[0] = (short)f2bf(x.x); r[1] = (short)f2bf(x.y);
    r[2] = (short)f2bf(x.z); r[3] = (short)f2bf(x.w);
    r[4] = (short)f2bf(y.x); r[5] = (short)f2bf(y.y);
    r[6] = (short)f2bf(y.z); r[7] = (short)f2bf(y.w);
    return r;
}

// async global->LDS, 16 bytes per lane. Dest must be wave-uniform base +
// lane*16 (linear in thread id within the wave).
static __device__ __forceinline__ void gl_lds16(const u16* g, u16* l) {
    __builtin_amdgcn_global_load_lds(
        (const __attribute__((address_space(1))) void*)g,
        (__attribute__((address_space(3))) void*)l, 16, 0, 0);
}

// ===========================================================================
// MAIN PATH (needs ~48.2 MB of d_ws)
// ===========================================================================

// ---------------------------------------------------------------------------
// Pass 1 (R7): 2 rows per wave, all loads issued up front (ILP), 16B bf16
// stores (short8). Blocks 0..2 additionally zero rs1/cs1/rs2. No LDS, no
// __syncthreads. Rows 0..4095: img (dot txt[r]); 4096..8191: txt;
// 8192..24575: other (dot txt[r>>2]).
// ---------------------------------------------------------------------------
__global__ __launch_bounds__(256) void convert_diag8z(
    const float* __restrict__ img, const float* __restrict__ txt,
    const float* __restrict__ other,
    u16* __restrict__ img_bf, u16* __restrict__ txt_bf, u16* __restrict__ oth_bf,
    float* __restrict__ partials, float* __restrict__ zero_region)
{
    if (blockIdx.x < 3) {
        float4* z = (float4*)zero_region + (size_t)blockIdx.x * 1024;
#pragma unroll
        for (int k = 0; k < 4; ++k)
            z[k * 256 + threadIdx.x] = (float4){0.f, 0.f, 0.f, 0.f};
    }

    const int wave = threadIdx.x >> 6;
    const int lane = threadIdx.x & 63;
    const int row0 = blockIdx.x * 8 + wave * 2;
    const int e    = lane * 8;          // elems [e, e+8) and [512+e, 512+e+8)

#pragma unroll
    for (int rr = 0; rr < 2; ++rr) {
        const int row = row0 + rr;

        const float* src;
        const float* dotsrc = nullptr;
        u16* dst;
        float* part = nullptr;

        if (row < B_SZ) {
            src    = img + (size_t)row * D_SZ;
            dst    = img_bf + (size_t)row * D_SZ;
            dotsrc = txt + (size_t)row * D_SZ;
            part   = partials + row;                       // -> dsum pool
        } else if (row < 2 * B_SZ) {
            const int r = row - B_SZ;
            src = txt + (size_t)r * D_SZ;
            dst = txt_bf + (size_t)r * D_SZ;
        } else {
            const int r = row - 2 * B_SZ;                  // 0..16383
            src    = other + (size_t)r * D_SZ;
            dst    = oth_bf + (size_t)r * D_SZ;
            dotsrc = txt + (size_t)(r >> 2) * D_SZ;
            part   = partials + B_SZ + r;                  // -> msum pool
        }

        // issue all 4 source loads (and 4 dot loads) before any use
        float4 a0 = *(const float4*)(src + e);
        float4 a1 = *(const float4*)(src + e + 4);
        float4 a2 = *(const float4*)(src + 512 + e);
        float4 a3 = *(const float4*)(src + 512 + e + 4);

        float s = 0.f;
        if (dotsrc) {
            float4 b0 = *(const float4*)(dotsrc + e);
            float4 b1 = *(const float4*)(dotsrc + e + 4);
            float4 b2 = *(const float4*)(dotsrc + 512 + e);
            float4 b3 = *(const float4*)(dotsrc + 512 + e + 4);
            s  = a0.x * b0.x + a0.y * b0.y + a0.z * b0.z + a0.w * b0.w;
            s += a1.x * b1.x + a1.y * b1.y + a1.z * b1.z + a1.w * b1.w;
            s += a2.x * b2.x + a2.y * b2.y + a2.z * b2.z + a2.w * b2.w;
            s += a3.x * b3.x + a3.y * b3.y + a3.z * b3.z + a3.w * b3.w;
        }

        *(bf16x8_t*)(dst + e)       = pack8(a0, a1);   // 16B store
        *(bf16x8_t*)(dst + 512 + e) = pack8(a2, a3);   // 16B store

        if (part) {
#pragma unroll
            for (int d = 1; d < 64; d <<= 1) s += __shfl_xor(s, d);
            if (lane == 0) part[0] = s * INV_T;
        }
    }
}

// ---------------------------------------------------------------------------
// Pass 2 (reverted to R2/R5 -- best measured: 233-251 us, ~747 TF, at the
// 2-phase structure-class ceiling; R6's 128x256/BK=32 occupancy experiment
// regressed via 2x HBM traffic + too-short compute phases):
// 256x256-tile, BK=64, 8-wave (2Mx4N), double-buffered bf16 MFMA GEMM.
// ONE barrier + ONE vmcnt per K-tile. LDS swizzle both-sides (0 conflicts).
// Blocks 0..255 = img x txt (row+col sums), 256..1279 = txt x oth (rowsum).
// ---------------------------------------------------------------------------
__global__ __launch_bounds__(512, 2) void gemm_fused(
    const u16* __restrict__ img_bf, const u16* __restrict__ txt_bf,
    const u16* __restrict__ oth_bf, float* __restrict__ rs1,
    float* __restrict__ cs1, float* __restrict__ rs2)
{
    __shared__ u16 lds[2][2][256][64];   // [dbuf][0=A,1=B][row][k] = 128 KiB

    // segment select + XCD-aware chunked swizzle (per-segment, both /8)
    const int bid0 = blockIdx.x;
    const u16 *X, *Y;
    float *rowsum, *colsum;
    int lb, gx, nloc;
    if (bid0 < 256) {
        X = img_bf; Y = txt_bf; rowsum = rs1; colsum = cs1;
        lb = bid0;       gx = 16; nloc = 256;
    } else {
        X = txt_bf; Y = oth_bf; rowsum = rs2; colsum = nullptr;
        lb = bid0 - 256; gx = 64; nloc = 1024;
    }
    const int chunk = nloc >> 3;
    lb = (lb & 7) * chunk + (lb >> 3);
    const int m0 = (lb / gx) * 256;
    const int n0 = (lb % gx) * 256;

    const int t    = threadIdx.x;
    const int lane = t & 63;
    const int w    = t >> 6;          // 0..7
    const int wrm  = (w >> 2) * 128;  // wave M offset (0/128)
    const int wcn  = (w & 3) * 64;    // wave N offset (0/64/128/192)
    const int lr   = lane & 15;
    const int q    = lane >> 4;
    const int swz  = lr & 7;          // == (row & 7) for all fragment rows

    // per-thread staging offsets: thread covers 16B chunks c = i*512+t of a
    // 128x64 half-tile; global source chunk is inverse-swizzled so the
    // linear LDS write yields the swizzled layout.
    int goff[2], loff[2];
#pragma unroll
    for (int i = 0; i < 2; ++i) {
        const int c  = i * 512 + t;
        const int r  = c >> 3;                        // row in half-tile
        const int lc = (c & 7) ^ (r & 7);             // logical 16B chunk
        goff[i] = r * D_SZ + lc * 8;
        loff[i] = c * 8;
    }

    const u16* gA0 = X + (size_t)m0 * D_SZ;
    const u16* gA1 = gA0 + (size_t)128 * D_SZ;
    const u16* gB0 = Y + (size_t)n0 * D_SZ;
    const u16* gB1 = gB0 + (size_t)128 * D_SZ;

    auto stage = [&](u16* dst, const u16* gsrc, int k0) {
#pragma unroll
        for (int i = 0; i < 2; ++i)
            gl_lds16(gsrc + k0 + goff[i], dst + loff[i]);
    };

    f32x4_t acc[8][4];
#pragma unroll
    for (int i = 0; i < 8; ++i)
#pragma unroll
        for (int jj = 0; jj < 4; ++jj) acc[i][jj] = (f32x4_t){0.f, 0.f, 0.f, 0.f};

    // ---- prologue: stage tile 0 into buf 0, wait, barrier ----
    stage(&lds[0][0][0][0],   gA0, 0);
    stage(&lds[0][0][128][0], gA1, 0);
    stage(&lds[0][1][0][0],   gB0, 0);
    stage(&lds[0][1][128][0], gB1, 0);
    asm volatile("s_waitcnt vmcnt(0)" ::: "memory");
    __builtin_amdgcn_s_barrier();
    CFENCE();

    const int NT = D_SZ / 64;   // 16
    for (int j = 0; j < NT; ++j) {
        const int c = j & 1;
        const u16* As = &lds[c][0][0][0];
        const u16* Bs = &lds[c][1][0][0];

        // prefetch tile j+1 into the other buffer (VMEM, flies under compute)
        if (j + 1 < NT) {
            const int k0 = (j + 1) * 64;
            stage(&lds[c ^ 1][0][0][0],   gA0, k0);
            stage(&lds[c ^ 1][0][128][0], gA1, k0);
            stage(&lds[c ^ 1][1][0][0],   gB0, k0);
            stage(&lds[c ^ 1][1][128][0], gB1, k0);
        }

        bf16x8_t bfr[2][4], afr[2][4];
#pragma unroll
        for (int kk = 0; kk < 2; ++kk) {
            const int ch = ((kk << 2) | q) ^ swz;
#pragma unroll
            for (int nt = 0; nt < 4; ++nt)
                bfr[kk][nt] = *(const bf16x8_t*)(Bs + (wcn + nt * 16 + lr) * 64 + ch * 8);
#pragma unroll
            for (int mt = 0; mt < 4; ++mt)
                afr[kk][mt] = *(const bf16x8_t*)(As + (wrm + mt * 16 + lr) * 64 + ch * 8);
        }
#pragma unroll
        for (int kk = 0; kk < 2; ++kk)
#pragma unroll
            for (int mt = 0; mt < 4; ++mt)
#pragma unroll
                for (int nt = 0; nt < 4; ++nt)
                    acc[mt][nt] = __builtin_amdgcn_mfma_f32_16x16x32_bf16(
                        afr[kk][mt], bfr[kk][nt], acc[mt][nt], 0, 0, 0);

        // high half of the A panel
#pragma unroll
        for (int kk = 0; kk < 2; ++kk) {
            const int ch = ((kk << 2) | q) ^ swz;
#pragma unroll
            for (int mt = 0; mt < 4; ++mt)
                afr[kk][mt] = *(const bf16x8_t*)(As + (wrm + (4 + mt) * 16 + lr) * 64 + ch * 8);
        }
#pragma unroll
        for (int kk = 0; kk < 2; ++kk)
#pragma unroll
            for (int mt = 0; mt < 4; ++mt)
#pragma unroll
                for (int nt = 0; nt < 4; ++nt)
                    acc[4 + mt][nt] = __builtin_amdgcn_mfma_f32_16x16x32_bf16(
                        afr[kk][mt], bfr[kk][nt], acc[4 + mt][nt], 0, 0, 0);

        // tile boundary: next tile's loads landed (issued a full tile ago);
        // all waves done reading buf c (so tile j+2 may overwrite it next).
        asm volatile("s_waitcnt vmcnt(0)" ::: "memory");
        __builtin_amdgcn_s_barrier();
        CFENCE();
    }

    // Epilogue. C/D layout: row = wrm + mt*16 + q*4 + r, col = wcn + nt*16 + lr.
    float rowp[8][4];
#pragma unroll
    for (int mt = 0; mt < 8; ++mt)
#pragma unroll
        for (int r = 0; r < 4; ++r) rowp[mt][r] = 0.f;

#pragma unroll
    for (int nt = 0; nt < 4; ++nt) {
        float colp = 0.f;
#pragma unroll
        for (int mt = 0; mt < 8; ++mt) {
#pragma unroll
            for (int r = 0; r < 4; ++r) {
                float e = __expf(acc[mt][nt][r] * INV_T);
                colp += e;
                rowp[mt][r] += e;
            }
        }
        if (colsum) {
            colp += __shfl_xor(colp, 16);
            colp += __shfl_xor(colp, 32);
            if (q == 0)
                atomicAdd(&colsum[n0 + wcn + nt * 16 + lr], colp);
        }
    }
#pragma unroll
    for (int mt = 0; mt < 8; ++mt) {
#pragma unroll
        for (int r = 0; r < 4; ++r) {
            float rp = rowp[mt][r];
            rp += __shfl_xor(rp, 1);
            rp += __shfl_xor(rp, 2);
            rp += __shfl_xor(rp, 4);
            rp += __shfl_xor(rp, 8);
            if (lr == 0)
                atomicAdd(&rowsum[m0 + wrm + mt * 16 + 4 * q + r], rp);
        }
    }
}

// ---------------------------------------------------------------------------
// Finalize: one 1024-thread block, float4 loads, wave shuffle + LDS reduce.
// ---------------------------------------------------------------------------
__global__ __launch_bounds__(1024) void finalize_wide(
    const float* __restrict__ rs1, const float* __restrict__ cs1,
    const float* __restrict__ rs2, const float* __restrict__ partials,
    float* __restrict__ out)
{
    const int t = threadIdx.x;   // 0..1023

    float4 a = ((const float4*)rs1)[t];
    float4 b = ((const float4*)cs1)[t];
    float4 c = ((const float4*)rs2)[t];
    float4 p = ((const float4*)partials)[t];
    float4 m0 = ((const float4*)(partials + B_SZ))[t];
    float4 m1 = ((const float4*)(partials + B_SZ))[t + 1024];
    float4 m2 = ((const float4*)(partials + B_SZ))[t + 2048];
    float4 m3 = ((const float4*)(partials + B_SZ))[t + 3072];
    float4 m4 = ((const float4*)(partials + B_SZ))[t + 4096];

    float s1 = __logf(a.x) + __logf(a.y) + __logf(a.z) + __logf(a.w);
    float s2 = __logf(b.x) + __logf(b.y) + __logf(b.z) + __logf(b.w);
    float s3 = __logf(c.x) + __logf(c.y) + __logf(c.z) + __logf(c.w);
    float pd = p.x + p.y + p.z + p.w;
    float pm = (m0.x + m0.y + m0.z + m0.w) + (m1.x + m1.y + m1.z + m1.w)
             + (m2.x + m2.y + m2.z + m2.w) + (m3.x + m3.y + m3.z + m3.w)
             + (m4.x + m4.y + m4.z + m4.w);

#pragma unroll
    for (int d = 1; d < 64; d <<= 1) {
        s1 += __shfl_xor(s1, d); s2 += __shfl_xor(s2, d);
        s3 += __shfl_xor(s3, d); pd += __shfl_xor(pd, d);
        pm += __shfl_xor(pm, d);
    }
    __shared__ float red[5][16];
    const int w = t >> 6, lane = t & 63;
    if (lane == 0) {
        red[0][w] = s1; red[1][w] = s2; red[2][w] = s3;
        red[3][w] = pd; red[4][w] = pm;
    }
    __syncthreads();
    if (t == 0) {
        float S1 = 0.f, S2 = 0.f, S3 = 0.f, DS = 0.f, MS = 0.f;
#pragma unroll
        for (int i = 0; i < 16; ++i) {
            S1 += red[0][i]; S2 += red[1][i]; S3 += red[2][i];
            DS += red[3][i]; MS += red[4][i];
        }
        const float invB = 1.0f / (float)B_SZ;
        out[0] = 0.5f * (S1 + S2) * invB - DS * invB
               + 0.5f * (S3 * invB - MS / ((float)B_SZ * K_SZ));
    }
}

// ===========================================================================
// FALLBACK PATH (used only if d_ws is too small) ----------------------------
// ===========================================================================
template <bool COLSUM>
__global__ __launch_bounds__(256) void gemm_expsum(
    const float* __restrict__ X, const float* __restrict__ Y,
    float* __restrict__ rowsum, float* __restrict__ colsum)
{
    __shared__ u16 As[128][32];
    __shared__ u16 Bs[128][32];
    const int m0 = blockIdx.y * 128, n0 = blockIdx.x * 128;
    const int tid = threadIdx.x, lane = tid & 63, w = tid >> 6;
    const int wm = (w & 1) * 64, wn = (w >> 1) * 64;
    const int lr = lane & 15, q = lane >> 4;
    f32x4_t acc[4][4];
#pragma unroll
    for (int i = 0; i < 4; i++)
#pragma unroll
        for (int j = 0; j < 4; j++) acc[i][j] = (f32x4_t){0.f, 0.f, 0.f, 0.f};
    const int kv = (tid & 7) * 4, r0 = tid >> 3;
    const float* xb = X + (size_t)(m0 + r0) * D_SZ + kv;
    const float* yb = Y + (size_t)(n0 + r0) * D_SZ + kv;
    for (int k0 = 0; k0 < D_SZ; k0 += 32) {
#pragma unroll
        for (int i = 0; i < 4; i++) {
            float4 a = *(const float4*)(xb + (size_t)(32 * i) * D_SZ + k0);
            float4 b = *(const float4*)(yb + (size_t)(32 * i) * D_SZ + k0);
            ushort4 ua, ub;
            ua.x = f2bf(a.x); ua.y = f2bf(a.y); ua.z = f2bf(a.z); ua.w = f2bf(a.w);
            ub.x = f2bf(b.x); ub.y = f2bf(b.y); ub.z = f2bf(b.z); ub.w = f2bf(b.w);
            *(ushort4*)&As[r0 + 32 * i][kv] = ua;
            *(ushort4*)&Bs[r0 + 32 * i][kv] = ub;
        }
        __syncthreads();
        bf16x8_t af[4], bfr[4];
#pragma unroll
        for (int mt = 0; mt < 4; mt++)
            af[mt] = *(const bf16x8_t*)&As[wm + 16 * mt + lr][8 * q];
#pragma unroll
        for (int nt = 0; nt < 4; nt++)
            bfr[nt] = *(const bf16x8_t*)&Bs[wn + 16 * nt + lr][8 * q];
#pragma unroll
        for (int mt = 0; mt < 4; mt++)
#pragma unroll
            for (int nt = 0; nt < 4; nt++)
                acc[mt][nt] = __builtin_amdgcn_mfma_f32_16x16x32_bf16(
                    af[mt], bfr[nt], acc[mt][nt], 0, 0, 0);
        __syncthreads();
    }
    float rowp[4][4];
#pragma unroll
    for (int mt = 0; mt < 4; mt++)
#pragma unroll
        for (int r = 0; r < 4; r++) rowp[mt][r] = 0.f;
#pragma unroll
    for (int nt = 0; nt < 4; nt++) {
        float colp = 0.f;
#pragma unroll
        for (int mt = 0; mt < 4; mt++)
#pragma unroll
            for (int r = 0; r < 4; r++) {
                float e = __expf(acc[mt][nt][r] * INV_T);
                colp += e; rowp[mt][r] += e;
            }
        if (COLSUM) {
            colp += __shfl_xor(colp, 16);
            colp += __shfl_xor(colp, 32);
            if (q == 0) atomicAdd(&colsum[n0 + wn + 16 * nt + lr], colp);
        }
    }
#pragma unroll
    for (int mt = 0; mt < 4; mt++)
#pragma unroll
        for (int r = 0; r < 4; r++) {
            float rp = rowp[mt][r];
            rp += __shfl_xor(rp, 1); rp += __shfl_xor(rp, 2);
            rp += __shfl_xor(rp, 4); rp += __shfl_xor(rp, 8);
            if (lr == 0) atomicAdd(&rowsum[m0 + wm + 16 * mt + 4 * q + r], rp);
        }
}

__global__ __launch_bounds__(256) void diag_kernel(
    const float* __restrict__ img, const float* __restrict__ txt,
    const float* __restrict__ other, float* __restrict__ dm)
{
    const int gw = blockIdx.x * 4 + (threadIdx.x >> 6);
    const int lane = threadIdx.x & 63;
    const float *pa, *pb; float* target;
    if (gw < B_SZ) {
        pa = img + (size_t)gw * D_SZ; pb = txt + (size_t)gw * D_SZ; target = dm;
    } else {
        const int g2 = gw - B_SZ;
        pa = other + (size_t)g2 * D_SZ; pb = txt + (size_t)(g2 >> 2) * D_SZ;
        target = dm + 1;
    }
    float s = 0.f;
#pragma unroll
    for (int j = 0; j < 4; j++) {
        float4 a = *(const float4*)(pa + 4 * (lane + 64 * j));
        float4 b = *(const float4*)(pb + 4 * (lane + 64 * j));
        s += a.x * b.x + a.y * b.y + a.z * b.z + a.w * b.w;
    }
#pragma unroll
    for (int d = 1; d < 64; d <<= 1) s += __shfl_xor(s, d);
    if (lane == 0) atomicAdd(target, s * INV_T);
}

__global__ __launch_bounds__(256) void finalize_atomic(
    const float* __restrict__ rs1, const float* __restrict__ cs1,
    const float* __restrict__ rs2, const float* __restrict__ dm,
    float* __restrict__ out)
{
    float s1 = 0.f, s2 = 0.f, s3 = 0.f;
    for (int i = threadIdx.x; i < B_SZ; i += 256) {
        s1 += __logf(rs1[i]); s2 += __logf(cs1[i]); s3 += __logf(rs2[i]);
    }
#pragma unroll
    for (int d = 1; d < 64; d <<= 1) {
        s1 += __shfl_xor(s1, d); s2 += __shfl_xor(s2, d); s3 += __shfl_xor(s3, d);
    }
    __shared__ float red[3][4];
    const int w = threadIdx.x >> 6, lane = threadIdx.x & 63;
    if (lane == 0) { red[0][w] = s1; red[1][w] = s2; red[2][w] = s3; }
    __syncthreads();
    if (threadIdx.x == 0) {
        float S1 = red[0][0] + red[0][1] + red[0][2] + red[0][3];
        float S2 = red[1][0] + red[1][1] + red[1][2] + red[1][3];
        float S3 = red[2][0] + red[2][1] + red[2][2] + red[2][3];
        const float invB = 1.0f / (float)B_SZ;
        out[0] = 0.5f * (S1 + S2) * invB - dm[0] * invB
               + 0.5f * (S3 * invB - dm[1] / ((float)B_SZ * K_SZ));
    }
}

// ===========================================================================
extern "C" void kernel_launch(void* const* d_in, const int* in_sizes, int n_in,
                              void* d_out, int out_size, void* d_ws, size_t ws_size,
                              hipStream_t stream) {
    const float* img   = (const float*)d_in[0];
    const float* txt   = (const float*)d_in[1];
    const float* other = (const float*)d_in[2];
    float* out = (float*)d_out;
    float* ws  = (float*)d_ws;

    // float-region layout
    float* rs1      = ws;                    // [4096]
    float* cs1      = ws + B_SZ;             // [4096]
    float* rs2      = ws + 2 * B_SZ;         // [4096]
    float* partials = ws + 3 * B_SZ;         // [20480]  (main path)
    float* dm       = ws + 3 * B_SZ;         // [2]      (fallback path)

    const size_t hdr_floats = 3 * B_SZ + B_SZ + B_SZ * K_SZ;   // 32768
    const size_t bf_bytes   = (size_t)(2 * B_SZ + B_SZ * K_SZ) * D_SZ * 2; // 48 MB
    const size_t need = hdr_floats * sizeof(float) + bf_bytes;

    if (ws_size >= need) {
        u16* img_bf = (u16*)(ws + hdr_floats);
        u16* txt_bf = img_bf + (size_t)B_SZ * D_SZ;
        u16* oth_bf = txt_bf + (size_t)B_SZ * D_SZ;

        hipLaunchKernelGGL(convert_diag8z, dim3((2 * B_SZ + B_SZ * K_SZ) / 8),
                           dim3(256), 0, stream, img, txt, other,
                           img_bf, txt_bf, oth_bf, partials, rs1);
        hipLaunchKernelGGL(gemm_fused, dim3(1280), dim3(512), 0, stream,
                           img_bf, txt_bf, oth_bf, rs1, cs1, rs2);
        hipLaunchKernelGGL(finalize_wide, dim3(1), dim3(1024), 0, stream,
                           rs1, cs1, rs2, partials, out);
    } else {
        hipMemsetAsync(d_ws, 0, (3 * B_SZ + 2) * sizeof(float), stream);
        hipLaunchKernelGGL((gemm_expsum<true>), dim3(B_SZ / 128, B_SZ / 128),
                           dim3(256), 0, stream, img, txt, rs1, cs1);
        hipLaunchKernelGGL((gemm_expsum<false>),
                           dim3(B_SZ * K_SZ / 128, B_SZ / 128), dim3(256), 0,
                           stream, txt, other, rs2, nullptr);
        hipLaunchKernelGGL(diag_kernel, dim3((B_SZ + B_SZ * K_SZ) / 4),
                           dim3(256), 0, stream, img, txt, other, dm);
        hipLaunchKernelGGL(finalize_atomic, dim3(1), dim3(256), 0, stream,
                           rs1, cs1, rs2, dm, out);
    }
}